// Round 1
// baseline (252.486 us; speedup 1.0000x reference)
//
#include <hip/hip_runtime.h>

typedef __bf16 bf16x8 __attribute__((ext_vector_type(8)));
typedef float f32x4 __attribute__((ext_vector_type(4)));

#define SCALE_F 0.014731391274719738f   /* 1/sqrt(9*512) */
#define SCALE2_F 2.170138888888889e-4f  /* 1/4608 */

__device__ __forceinline__ ushort f2bf(float f) {
    uint x = __float_as_uint(f);
    uint r = (x + 0x7fffu + ((x >> 16) & 1u)) >> 16;
    return (ushort)r;
}

__device__ __forceinline__ void async_cp16(const void* g, void* l) {
    __builtin_amdgcn_global_load_lds(
        (const __attribute__((address_space(1))) void*)g,
        (__attribute__((address_space(3))) void*)l, 16, 0, 0);
}

// ---------------- prep kernels ----------------

// Q[ci*512+co] = scale^2 * sum_tap kernel[tap,ci,co]^2
__global__ void k_q(const float* __restrict__ kern, float* __restrict__ Q) {
    int idx = blockIdx.x * 256 + threadIdx.x;   // ci*512+co, 262144 total
    float s = 0.f;
#pragma unroll
    for (int t = 0; t < 9; ++t) { float v = kern[t * 262144 + idx]; s += v * v; }
    Q[idx] = s * SCALE2_F;
}

// sigma[b*512+co] = rsqrt(sum_ci style^2 * Q + eps)
__global__ void k_sigma(const float* __restrict__ style, const float* __restrict__ Q,
                        float* __restrict__ sig) {
    __shared__ float s2[512];
    int b = blockIdx.x, t = threadIdx.x;   // 512 threads
    float s = style[b * 512 + t];
    s2[t] = s * s;
    __syncthreads();
    float acc = 0.f;
#pragma unroll 8
    for (int ci = 0; ci < 512; ++ci) acc += s2[ci] * Q[ci * 512 + t];
    sig[b * 512 + t] = rsqrtf(acc + 1e-8f);
}

// wT[b][tap][co][ci] = bf16(scale * kernel[tap,ci,co] * style[b,ci] * sigma[b,co])
__global__ void k_wt(const float* __restrict__ kern, const float* __restrict__ style,
                     const float* __restrict__ sig, ushort* __restrict__ wT) {
    __shared__ ushort tile[64 * 65];
    int b = blockIdx.z, tap = blockIdx.y;
    int ci0 = (blockIdx.x >> 3) << 6, co0 = (blockIdx.x & 7) << 6;
    int t = threadIdx.x;
    int col = t & 63, rq = t >> 6;
#pragma unroll
    for (int r = 0; r < 16; ++r) {
        int ci_l = r * 4 + rq;
        float v = kern[(size_t)(tap * 512 + ci0 + ci_l) * 512 + co0 + col];
        float val = SCALE_F * v * style[b * 512 + ci0 + ci_l] * sig[b * 512 + co0 + col];
        tile[ci_l * 65 + col] = f2bf(val);
    }
    __syncthreads();
#pragma unroll
    for (int r = 0; r < 4; ++r) {
        int q = r * 256 + t;
        int co_l = q >> 4, ciq = (q & 15) << 2;
        uint lo = (uint)tile[ciq * 65 + co_l] | ((uint)tile[(ciq + 1) * 65 + co_l] << 16);
        uint hi = (uint)tile[(ciq + 2) * 65 + co_l] | ((uint)tile[(ciq + 3) * 65 + co_l] << 16);
        *(uint2*)(&wT[((size_t)(b * 9 + tap) * 512 + co0 + co_l) * 512 + ci0 + ciq]) =
            make_uint2(lo, hi);
    }
}

// xpad[b][hp][wp][ci] bf16, hp/wp in [0,66), zero halo of 1, interior = x[b][hp-1][wp-1][ci]
__global__ void k_xpad(const float* __restrict__ x, ushort* __restrict__ xp) {
    int idx = blockIdx.x * 256 + threadIdx.x;   // 2,230,272 total
    int pos = idx >> 6, e = idx & 63;
    int b = pos / 4356, rem = pos - b * 4356;
    int hp = rem / 66, wp = rem - hp * 66;
    int ci0 = e << 3;
    uint4 o = make_uint4(0u, 0u, 0u, 0u);
    if (hp >= 1 && hp <= 64 && wp >= 1 && wp <= 64) {
        const float4* s =
            (const float4*)(x + (((size_t)(b * 4096 + (hp - 1) * 64 + (wp - 1))) << 9) + ci0);
        float4 v0 = s[0], v1 = s[1];
        o.x = (uint)f2bf(v0.x) | ((uint)f2bf(v0.y) << 16);
        o.y = (uint)f2bf(v0.z) | ((uint)f2bf(v0.w) << 16);
        o.z = (uint)f2bf(v1.x) | ((uint)f2bf(v1.y) << 16);
        o.w = (uint)f2bf(v1.z) | ((uint)f2bf(v1.w) << 16);
    }
    *(uint4*)(xp + (((size_t)pos) << 9) + ci0) = o;
}

// ---------------- main conv (implicit GEMM, bf16 MFMA) ----------------
// grid (32 mt, 4 nt, 8 b), block 256 (4 waves, 2x2 of 64x64)
// A tile: [128 m][64 k] bf16, B tile: [128 co][64 k] bf16, both XOR-swizzled by
// 16B-chunk: stored chunk c holds data chunk c ^ (row&7); global source is
// pre-swizzled so global_load_lds (linear LDS dest) lands data correctly.
__global__ __launch_bounds__(256, 2) void conv_mfma(const ushort* __restrict__ xpad,
                                                    const ushort* __restrict__ wT,
                                                    float* __restrict__ out) {
    int mt = blockIdx.x, nt = blockIdx.y, b = blockIdx.z;
    int tid = threadIdx.x;
    int lane = tid & 63, wv = tid >> 6;
    int wm = (wv >> 1) * 64, wn = (wv & 1) * 64;

    __shared__ ushort As[2][128 * 64];
    __shared__ ushort Bs[2][128 * 64];

    // per-lane staging invariants: wave wv stages rows [wv*32, wv*32+32)
    const ushort* baseA[4];
    const ushort* baseB[4];
    int rl = lane >> 3;       // row within 8-row group
    int cL = lane & 7;        // stored chunk index
    {
#pragma unroll
        for (int i = 0; i < 4; ++i) {
            int row = wv * 32 + i * 8 + rl;
            int g = cL ^ (row & 7);          // data chunk this LDS slot must hold
            int hl = row >> 6, wq = row & 63;
            baseA[i] = xpad + (((size_t)((b * 66 + mt * 2 + hl) * 66 + wq)) << 9) + g * 8;
            baseB[i] = wT + (((size_t)(b * 4608 + nt * 128 + row)) << 9) + g * 8;
        }
    }

    f32x4 acc[4][4];
#pragma unroll
    for (int mi = 0; mi < 4; ++mi)
#pragma unroll
        for (int ni = 0; ni < 4; ++ni) acc[mi][ni] = (f32x4){0.f, 0.f, 0.f, 0.f};

    auto stage = [&](int buf, int offA, int offB) {
#pragma unroll
        for (int i = 0; i < 4; ++i)
            async_cp16(baseA[i] + offA, &As[buf][(wv * 32 + i * 8) * 64]);
#pragma unroll
        for (int i = 0; i < 4; ++i)
            async_cp16(baseB[i] + offB, &Bs[buf][(wv * 32 + i * 8) * 64]);
    };

    // kt = tap*8 + ci_chunk; 72 steps
    stage(0, 0, 0);
    for (int kt = 0; kt < 72; ++kt) {
        __syncthreads();   // staging of buf[kt&1] complete (vmcnt drained at barrier)
        if (kt + 1 < 72) {
            int t = kt + 1;
            int tap = t >> 3, ci0 = (t & 7) << 6;
            int ky = tap / 3, kx = tap - ky * 3;
            stage(t & 1, (ky * 66 + kx) * 512 + ci0, tap * 262144 + ci0);
        }
        int buf = kt & 1;
        const char* ab = (const char*)&As[buf][0];
        const char* bb = (const char*)&Bs[buf][0];
#pragma unroll
        for (int kk = 0; kk < 2; ++kk) {
            bf16x8 af[4], bfr[4];
            int c = kk * 4 + (lane >> 4);
#pragma unroll
            for (int mi = 0; mi < 4; ++mi) {
                int row = wm + mi * 16 + (lane & 15);
                af[mi] = *(const bf16x8*)(ab + row * 128 + ((c ^ (row & 7)) * 16));
            }
#pragma unroll
            for (int ni = 0; ni < 4; ++ni) {
                int row = wn + ni * 16 + (lane & 15);
                bfr[ni] = *(const bf16x8*)(bb + row * 128 + ((c ^ (row & 7)) * 16));
            }
#pragma unroll
            for (int mi = 0; mi < 4; ++mi)
#pragma unroll
                for (int ni = 0; ni < 4; ++ni)
                    acc[mi][ni] = __builtin_amdgcn_mfma_f32_16x16x32_bf16(
                        af[mi], bfr[ni], acc[mi][ni], 0, 0, 0);
        }
    }

    // epilogue: D[(lane>>4)*4+r][lane&15] per 16x16 fragment
#pragma unroll
    for (int mi = 0; mi < 4; ++mi) {
#pragma unroll
        for (int ni = 0; ni < 4; ++ni) {
#pragma unroll
            for (int r = 0; r < 4; ++r) {
                int m = mt * 128 + wm + mi * 16 + (lane >> 4) * 4 + r;
                int co = nt * 128 + wn + ni * 16 + (lane & 15);
                out[(((size_t)b * 4096 + m) << 9) + co] = acc[mi][ni][r];
            }
        }
    }
}

// ---------------- launch ----------------

extern "C" void kernel_launch(void* const* d_in, const int* in_sizes, int n_in,
                              void* d_out, int out_size, void* d_ws, size_t ws_size,
                              hipStream_t stream) {
    const float* x = (const float*)d_in[0];      // [8,64,64,512]
    const float* style = (const float*)d_in[1];  // [8,512]
    const float* kern = (const float*)d_in[2];   // [3,3,512,512]
    float* out = (float*)d_out;                  // [8,64,64,512]

    char* ws = (char*)d_ws;
    ushort* xpad = (ushort*)ws;                                // 35,684,352 B
    ushort* wT = (ushort*)(ws + 35684352);                     // 37,748,736 B
    float* Q = (float*)(ws + 35684352 + 37748736);             // 1,048,576 B
    float* sig = (float*)(ws + 35684352 + 37748736 + 1048576); // 16,384 B

    k_q<<<1024, 256, 0, stream>>>(kern, Q);
    k_sigma<<<8, 512, 0, stream>>>(style, Q, sig);
    k_wt<<<dim3(64, 9, 8), 256, 0, stream>>>(kern, style, sig, wT);
    k_xpad<<<8712, 256, 0, stream>>>(x, xpad);
    conv_mfma<<<dim3(32, 4, 8), 256, 0, stream>>>(xpad, wT, out);
}

// Round 2
// 203.032 us; speedup vs baseline: 1.2436x; 1.2436x over previous
//
#include <hip/hip_runtime.h>

typedef __bf16 bf16x8 __attribute__((ext_vector_type(8)));
typedef float f32x4 __attribute__((ext_vector_type(4)));

#define SCALE_F 0.014731391274719738f   /* 1/sqrt(9*512) */
#define SCALE2_F 2.170138888888889e-4f  /* 1/4608 */

__device__ __forceinline__ ushort f2bf(float f) {
    uint x = __float_as_uint(f);
    uint r = (x + 0x7fffu + ((x >> 16) & 1u)) >> 16;
    return (ushort)r;
}

__device__ __forceinline__ void async_cp16(const void* g, void* l) {
    __builtin_amdgcn_global_load_lds(
        (const __attribute__((address_space(1))) void*)g,
        (__attribute__((address_space(3))) void*)l, 16, 0, 0);
}

// ---------------- prep kernels (unchanged from R1) ----------------

__global__ void k_q(const float* __restrict__ kern, float* __restrict__ Q) {
    int idx = blockIdx.x * 256 + threadIdx.x;
    float s = 0.f;
#pragma unroll
    for (int t = 0; t < 9; ++t) { float v = kern[t * 262144 + idx]; s += v * v; }
    Q[idx] = s * SCALE2_F;
}

__global__ void k_sigma(const float* __restrict__ style, const float* __restrict__ Q,
                        float* __restrict__ sig) {
    __shared__ float s2[512];
    int b = blockIdx.x, t = threadIdx.x;
    float s = style[b * 512 + t];
    s2[t] = s * s;
    __syncthreads();
    float acc = 0.f;
#pragma unroll 8
    for (int ci = 0; ci < 512; ++ci) acc += s2[ci] * Q[ci * 512 + t];
    sig[b * 512 + t] = rsqrtf(acc + 1e-8f);
}

__global__ void k_wt(const float* __restrict__ kern, const float* __restrict__ style,
                     const float* __restrict__ sig, ushort* __restrict__ wT) {
    __shared__ ushort tile[64 * 65];
    int b = blockIdx.z, tap = blockIdx.y;
    int ci0 = (blockIdx.x >> 3) << 6, co0 = (blockIdx.x & 7) << 6;
    int t = threadIdx.x;
    int col = t & 63, rq = t >> 6;
#pragma unroll
    for (int r = 0; r < 16; ++r) {
        int ci_l = r * 4 + rq;
        float v = kern[(size_t)(tap * 512 + ci0 + ci_l) * 512 + co0 + col];
        float val = SCALE_F * v * style[b * 512 + ci0 + ci_l] * sig[b * 512 + co0 + col];
        tile[ci_l * 65 + col] = f2bf(val);
    }
    __syncthreads();
#pragma unroll
    for (int r = 0; r < 4; ++r) {
        int q = r * 256 + t;
        int co_l = q >> 4, ciq = (q & 15) << 2;
        uint lo = (uint)tile[ciq * 65 + co_l] | ((uint)tile[(ciq + 1) * 65 + co_l] << 16);
        uint hi = (uint)tile[(ciq + 2) * 65 + co_l] | ((uint)tile[(ciq + 3) * 65 + co_l] << 16);
        *(uint2*)(&wT[((size_t)(b * 9 + tap) * 512 + co0 + co_l) * 512 + ci0 + ciq]) =
            make_uint2(lo, hi);
    }
}

__global__ void k_xpad(const float* __restrict__ x, ushort* __restrict__ xp) {
    int idx = blockIdx.x * 256 + threadIdx.x;
    int pos = idx >> 6, e = idx & 63;
    int b = pos / 4356, rem = pos - b * 4356;
    int hp = rem / 66, wp = rem - hp * 66;
    int ci0 = e << 3;
    uint4 o = make_uint4(0u, 0u, 0u, 0u);
    if (hp >= 1 && hp <= 64 && wp >= 1 && wp <= 64) {
        const float4* s =
            (const float4*)(x + (((size_t)(b * 4096 + (hp - 1) * 64 + (wp - 1))) << 9) + ci0);
        float4 v0 = s[0], v1 = s[1];
        o.x = (uint)f2bf(v0.x) | ((uint)f2bf(v0.y) << 16);
        o.y = (uint)f2bf(v0.z) | ((uint)f2bf(v0.w) << 16);
        o.z = (uint)f2bf(v1.x) | ((uint)f2bf(v1.y) << 16);
        o.w = (uint)f2bf(v1.z) | ((uint)f2bf(v1.w) << 16);
    }
    *(uint4*)(xp + (((size_t)pos) << 9) + ci0) = o;
}

// ---------------- main conv: 256x256 tile, BK=64, 8 waves, ring-buffered ----------------
// A-ring: 5 half-slots (128 rows x 64 k), B-ring: 4 half-slots. 144 KiB dynamic LDS.
// Schedule per group G (K-tile G of 72), phases q=0..3:
//   q0: read B-frags(8)+A-frags(mi0,1) | stage A-h1(G+1)
//   q1: read A-frags(mi2,3)            | stage A-h0(G+2)
//   q2: read A-frags(mi4,5)            | stage B-h0(G+2)
//   q3: read A-frags(mi6,7)            | stage B-h1(G+2) ... vmcnt(6) at group end
// Each phase: reads+stage -> s_barrier -> MFMA(16) -> s_barrier. Counted vmcnt only.
__global__ __launch_bounds__(512, 2) void conv_mfma(const ushort* __restrict__ xpad,
                                                    const ushort* __restrict__ wT,
                                                    float* __restrict__ out) {
    extern __shared__ char lds[];
    char* Alds = lds;                 // 5 * 16384
    char* Blds = lds + 5 * 16384;     // 4 * 16384

    const int mt = blockIdx.x;   // 16
    const int nt = blockIdx.y;   // 2
    const int b = blockIdx.z;    // 8
    const int tid = threadIdx.x;
    const int l = tid & 63, wv = tid >> 6;
    const int wm = (wv >> 2) * 128;
    const int wn = (wv & 3) * 64;
    const int ha = wv >> 2;          // A half this wave reads
    const int hb = (wv & 3) >> 1;    // B half this wave reads

    // staging geometry: lane l covers row (l>>3) of an 8-row group, stored chunk l&7
    const int rl = l >> 3;
    const int g = (l & 7) ^ rl;      // data chunk pre-swizzle
    const ushort* baseA[2][2];
    const ushort* baseB[2][2];
#pragma unroll
    for (int h = 0; h < 2; ++h)
#pragma unroll
        for (int i = 0; i < 2; ++i) {
            int rloc = wv * 16 + i * 8 + rl;   // 0..127 within half
            int R = h * 128 + rloc;            // 0..255 tile row
            baseA[h][i] = xpad + ((size_t)((b * 66 + mt * 4 + (R >> 6)) * 66 + (R & 63))) * 512 + g * 8;
            baseB[h][i] = wT + ((size_t)(b * 9 * 512 + nt * 256 + R)) * 512 + g * 8;
        }
    const int rowoff0 = (wv * 16) * 128;       // LDS byte offset of load slot 0
    const int rowoff1 = (wv * 16 + 8) * 128;   // load slot 1

    // per-tile global offsets (elements)
    auto offA = [](int t) -> int {
        int tap = t >> 3;
        int ky = (tap * 11) >> 5;
        int kx = tap - ky * 3;
        return (ky * 66 + kx) * 512 + ((t & 7) << 6);
    };
    auto offB = [](int t) -> int { return (t >> 3) * 262144 + ((t & 7) << 6); };

    auto stageA = [&](int h, int goff, int slot) {
        char* base = Alds + slot * 16384;
        async_cp16(baseA[h][0] + goff, base + rowoff0);
        async_cp16(baseA[h][1] + goff, base + rowoff1);
    };
    auto stageB = [&](int h, int goff, int slot) {
        char* base = Blds + slot * 16384;
        async_cp16(baseB[h][0] + goff, base + rowoff0);
        async_cp16(baseB[h][1] + goff, base + rowoff1);
    };

    f32x4 acc[8][4];
#pragma unroll
    for (int mi = 0; mi < 8; ++mi)
#pragma unroll
        for (int ni = 0; ni < 4; ++ni) acc[mi][ni] = (f32x4){0.f, 0.f, 0.f, 0.f};

    // prologue: issue A-h0(0), B-h0(0), B-h1(0), A-h1(0), A-h0(1), B-h0(1), B-h1(1)
    stageA(0, offA(0), 0);
    stageB(0, offB(0), 0);
    stageB(1, offB(0), 1);
    stageA(1, offA(0), 1);
    stageA(0, offA(1), 2);
    stageB(0, offB(1), 2);
    stageB(1, offB(1), 3);
    asm volatile("s_waitcnt vmcnt(6)" ::: "memory");
    __builtin_amdgcn_sched_barrier(0);
    __builtin_amdgcn_s_barrier();
    __builtin_amdgcn_sched_barrier(0);

    // frag-read lane invariants
    const int frow = l & 15;
    const int fchunk_base = l >> 4;   // 0..3
    const int fxor = l & 7;

    int ra0 = 0;  // (2G)%5
#pragma unroll 1
    for (int G = 0; G < 72; ++G) {
        const int rb0 = (G & 1) << 1;           // (2G)%4
        const int raSlot = (ra0 + ha >= 5) ? ra0 + ha - 5 : ra0 + ha;
        const int rbSlot = (rb0 + hb) & 3;
        const char* aB = Alds + raSlot * 16384;
        const char* bB = Blds + rbSlot * 16384;
        const int oA1 = offA(G + 1), oA2 = offA(G + 2), oB2 = offB(G + 2);
        const int sA1 = (ra0 + 3 >= 5) ? ra0 - 2 : ra0 + 3;   // (2G+3)%5
        const int sA2 = (ra0 + 4 >= 5) ? ra0 - 1 : ra0 + 4;   // (2G+4)%5

        bf16x8 bq[4][2];
#pragma unroll
        for (int q = 0; q < 4; ++q) {
            bf16x8 aq[2][2];
            if (q == 0) {
#pragma unroll
                for (int ni = 0; ni < 4; ++ni)
#pragma unroll
                    for (int kk = 0; kk < 2; ++kk) {
                        int r = (wn & 64) + ni * 16 + frow;
                        bq[ni][kk] = *(const bf16x8*)(bB + r * 128 +
                                                      (((kk * 4 + fchunk_base) ^ fxor) * 16));
                    }
            }
#pragma unroll
            for (int m2 = 0; m2 < 2; ++m2)
#pragma unroll
                for (int kk = 0; kk < 2; ++kk) {
                    int r = (2 * q + m2) * 16 + frow;
                    aq[m2][kk] = *(const bf16x8*)(aB + r * 128 +
                                                  (((kk * 4 + fchunk_base) ^ fxor) * 16));
                }
            // staging
            if (q == 0) { if (G <= 70) stageA(1, oA1, sA1); }
            if (q == 1) { if (G <= 69) stageA(0, oA2, sA2); }
            if (q == 2) { if (G <= 69) stageB(0, oB2, rb0); }
            if (q == 3) { if (G <= 69) stageB(1, oB2, (rb0 + 1) & 3); }

            __builtin_amdgcn_sched_barrier(0);
            __builtin_amdgcn_s_barrier();
            __builtin_amdgcn_sched_barrier(0);

            __builtin_amdgcn_s_setprio(1);
#pragma unroll
            for (int kk = 0; kk < 2; ++kk)
#pragma unroll
                for (int ni = 0; ni < 4; ++ni)
#pragma unroll
                    for (int m2 = 0; m2 < 2; ++m2)
                        acc[2 * q + m2][ni] = __builtin_amdgcn_mfma_f32_16x16x32_bf16(
                            aq[m2][kk], bq[ni][kk], acc[2 * q + m2][ni], 0, 0, 0);
            __builtin_amdgcn_s_setprio(0);

            if (q == 3) {
                if (G <= 69) {
                    asm volatile("s_waitcnt vmcnt(6)" ::: "memory");
                } else if (G == 70) {
                    asm volatile("s_waitcnt vmcnt(0)" ::: "memory");
                }
            }
            __builtin_amdgcn_sched_barrier(0);
            __builtin_amdgcn_s_barrier();
            __builtin_amdgcn_sched_barrier(0);
        }
        ra0 = (ra0 + 2 >= 5) ? ra0 - 3 : ra0 + 2;
    }

    // epilogue
#pragma unroll
    for (int mi = 0; mi < 8; ++mi) {
#pragma unroll
        for (int ni = 0; ni < 4; ++ni) {
#pragma unroll
            for (int r = 0; r < 4; ++r) {
                int m = mt * 256 + wm + mi * 16 + (l >> 4) * 4 + r;
                int co = nt * 256 + wn + ni * 16 + (l & 15);
                out[(((size_t)(b * 4096 + m)) << 9) + co] = acc[mi][ni][r];
            }
        }
    }
}

// ---------------- launch ----------------

extern "C" void kernel_launch(void* const* d_in, const int* in_sizes, int n_in,
                              void* d_out, int out_size, void* d_ws, size_t ws_size,
                              hipStream_t stream) {
    const float* x = (const float*)d_in[0];
    const float* style = (const float*)d_in[1];
    const float* kern = (const float*)d_in[2];
    float* out = (float*)d_out;

    char* ws = (char*)d_ws;
    ushort* xpad = (ushort*)ws;                                // 35,684,352 B
    ushort* wT = (ushort*)(ws + 35684352);                     // 37,748,736 B
    float* Q = (float*)(ws + 35684352 + 37748736);             // 1,048,576 B
    float* sig = (float*)(ws + 35684352 + 37748736 + 1048576); // 16,384 B

    (void)hipFuncSetAttribute((const void*)conv_mfma,
                              hipFuncAttributeMaxDynamicSharedMemorySize, 147456);

    k_q<<<1024, 256, 0, stream>>>(kern, Q);
    k_sigma<<<8, 512, 0, stream>>>(style, Q, sig);
    k_wt<<<dim3(64, 9, 8), 256, 0, stream>>>(kern, style, sig, wT);
    k_xpad<<<8712, 256, 0, stream>>>(x, xpad);
    conv_mfma<<<dim3(16, 2, 8), 512, 147456, stream>>>(xpad, wT, out);
}

// Round 3
// 195.120 us; speedup vs baseline: 1.2940x; 1.0405x over previous
//
#include <hip/hip_runtime.h>

typedef __bf16 bf16x8 __attribute__((ext_vector_type(8)));
typedef float f32x4 __attribute__((ext_vector_type(4)));

#define SCALE_F 0.014731391274719738f   /* 1/sqrt(9*512) */
#define SCALE2_F 2.170138888888889e-4f  /* 1/4608 */

__device__ __forceinline__ ushort f2bf(float f) {
    uint x = __float_as_uint(f);
    uint r = (x + 0x7fffu + ((x >> 16) & 1u)) >> 16;
    return (ushort)r;
}

__device__ __forceinline__ void async_cp16(const void* g, void* l) {
    __builtin_amdgcn_global_load_lds(
        (const __attribute__((address_space(1))) void*)g,
        (__attribute__((address_space(3))) void*)l, 16, 0, 0);
}

// ---------------- prep kernels (unchanged) ----------------

__global__ void k_q(const float* __restrict__ kern, float* __restrict__ Q) {
    int idx = blockIdx.x * 256 + threadIdx.x;
    float s = 0.f;
#pragma unroll
    for (int t = 0; t < 9; ++t) { float v = kern[t * 262144 + idx]; s += v * v; }
    Q[idx] = s * SCALE2_F;
}

__global__ void k_sigma(const float* __restrict__ style, const float* __restrict__ Q,
                        float* __restrict__ sig) {
    __shared__ float s2[512];
    int b = blockIdx.x, t = threadIdx.x;
    float s = style[b * 512 + t];
    s2[t] = s * s;
    __syncthreads();
    float acc = 0.f;
#pragma unroll 8
    for (int ci = 0; ci < 512; ++ci) acc += s2[ci] * Q[ci * 512 + t];
    sig[b * 512 + t] = rsqrtf(acc + 1e-8f);
}

__global__ void k_wt(const float* __restrict__ kern, const float* __restrict__ style,
                     const float* __restrict__ sig, ushort* __restrict__ wT) {
    __shared__ ushort tile[64 * 65];
    int b = blockIdx.z, tap = blockIdx.y;
    int ci0 = (blockIdx.x >> 3) << 6, co0 = (blockIdx.x & 7) << 6;
    int t = threadIdx.x;
    int col = t & 63, rq = t >> 6;
#pragma unroll
    for (int r = 0; r < 16; ++r) {
        int ci_l = r * 4 + rq;
        float v = kern[(size_t)(tap * 512 + ci0 + ci_l) * 512 + co0 + col];
        float val = SCALE_F * v * style[b * 512 + ci0 + ci_l] * sig[b * 512 + co0 + col];
        tile[ci_l * 65 + col] = f2bf(val);
    }
    __syncthreads();
#pragma unroll
    for (int r = 0; r < 4; ++r) {
        int q = r * 256 + t;
        int co_l = q >> 4, ciq = (q & 15) << 2;
        uint lo = (uint)tile[ciq * 65 + co_l] | ((uint)tile[(ciq + 1) * 65 + co_l] << 16);
        uint hi = (uint)tile[(ciq + 2) * 65 + co_l] | ((uint)tile[(ciq + 3) * 65 + co_l] << 16);
        *(uint2*)(&wT[((size_t)(b * 9 + tap) * 512 + co0 + co_l) * 512 + ci0 + ciq]) =
            make_uint2(lo, hi);
    }
}

__global__ void k_xpad(const float* __restrict__ x, ushort* __restrict__ xp) {
    int idx = blockIdx.x * 256 + threadIdx.x;
    int pos = idx >> 6, e = idx & 63;
    int b = pos / 4356, rem = pos - b * 4356;
    int hp = rem / 66, wp = rem - hp * 66;
    int ci0 = e << 3;
    uint4 o = make_uint4(0u, 0u, 0u, 0u);
    if (hp >= 1 && hp <= 64 && wp >= 1 && wp <= 64) {
        const float4* s =
            (const float4*)(x + (((size_t)(b * 4096 + (hp - 1) * 64 + (wp - 1))) << 9) + ci0);
        float4 v0 = s[0], v1 = s[1];
        o.x = (uint)f2bf(v0.x) | ((uint)f2bf(v0.y) << 16);
        o.y = (uint)f2bf(v0.z) | ((uint)f2bf(v0.w) << 16);
        o.z = (uint)f2bf(v1.x) | ((uint)f2bf(v1.y) << 16);
        o.w = (uint)f2bf(v1.z) | ((uint)f2bf(v1.w) << 16);
    }
    *(uint4*)(xp + (((size_t)pos) << 9) + ci0) = o;
}

// ---------------- main conv: 256x256 tile, BK=64, 8 waves, ring-buffered ----------------
// R3 change: 1D grid + bijective XCD swizzle (T1). Each XCD's contiguous chunk of
// 32 block-ids = one batch b (16 mt x 2 nt) -> per-XCD L2 working set 73MB -> 9.2MB.
__global__ __launch_bounds__(512, 2) void conv_mfma(const ushort* __restrict__ xpad,
                                                    const ushort* __restrict__ wT,
                                                    float* __restrict__ out) {
    extern __shared__ char lds[];
    char* Alds = lds;                 // 5 * 16384
    char* Blds = lds + 5 * 16384;     // 4 * 16384

    // XCD swizzle: hw assigns blockIdx.x round-robin to XCDs (xcd = wg % 8).
    // swz gives XCD k the contiguous chunk [k*32, k*32+32) of logical ids.
    const int wg = blockIdx.x;                      // 0..255
    const int swz = (wg & 7) * 32 + (wg >> 3);      // bijective (256 % 8 == 0)
    const int mt = swz & 15;
    const int nt = (swz >> 4) & 1;
    const int b = swz >> 5;

    const int tid = threadIdx.x;
    const int l = tid & 63, wv = tid >> 6;
    const int wm = (wv >> 2) * 128;
    const int wn = (wv & 3) * 64;
    const int ha = wv >> 2;          // A half this wave reads
    const int hb = (wv & 3) >> 1;    // B half this wave reads

    // staging geometry: lane l covers row (l>>3) of an 8-row group, stored chunk l&7
    const int rl = l >> 3;
    const int g = (l & 7) ^ rl;      // data chunk pre-swizzle
    const ushort* baseA[2][2];
    const ushort* baseB[2][2];
#pragma unroll
    for (int h = 0; h < 2; ++h)
#pragma unroll
        for (int i = 0; i < 2; ++i) {
            int rloc = wv * 16 + i * 8 + rl;   // 0..127 within half
            int R = h * 128 + rloc;            // 0..255 tile row
            baseA[h][i] = xpad + ((size_t)((b * 66 + mt * 4 + (R >> 6)) * 66 + (R & 63))) * 512 + g * 8;
            baseB[h][i] = wT + ((size_t)(b * 9 * 512 + nt * 256 + R)) * 512 + g * 8;
        }
    const int rowoff0 = (wv * 16) * 128;       // LDS byte offset of load slot 0
    const int rowoff1 = (wv * 16 + 8) * 128;   // load slot 1

    auto offA = [](int t) -> int {
        int tap = t >> 3;
        int ky = (tap * 11) >> 5;
        int kx = tap - ky * 3;
        return (ky * 66 + kx) * 512 + ((t & 7) << 6);
    };
    auto offB = [](int t) -> int { return (t >> 3) * 262144 + ((t & 7) << 6); };

    auto stageA = [&](int h, int goff, int slot) {
        char* base = Alds + slot * 16384;
        async_cp16(baseA[h][0] + goff, base + rowoff0);
        async_cp16(baseA[h][1] + goff, base + rowoff1);
    };
    auto stageB = [&](int h, int goff, int slot) {
        char* base = Blds + slot * 16384;
        async_cp16(baseB[h][0] + goff, base + rowoff0);
        async_cp16(baseB[h][1] + goff, base + rowoff1);
    };

    f32x4 acc[8][4];
#pragma unroll
    for (int mi = 0; mi < 8; ++mi)
#pragma unroll
        for (int ni = 0; ni < 4; ++ni) acc[mi][ni] = (f32x4){0.f, 0.f, 0.f, 0.f};

    // prologue
    stageA(0, offA(0), 0);
    stageB(0, offB(0), 0);
    stageB(1, offB(0), 1);
    stageA(1, offA(0), 1);
    stageA(0, offA(1), 2);
    stageB(0, offB(1), 2);
    stageB(1, offB(1), 3);
    asm volatile("s_waitcnt vmcnt(6)" ::: "memory");
    __builtin_amdgcn_sched_barrier(0);
    __builtin_amdgcn_s_barrier();
    __builtin_amdgcn_sched_barrier(0);

    const int frow = l & 15;
    const int fchunk_base = l >> 4;   // 0..3
    const int fxor = l & 7;

    int ra0 = 0;  // (2G)%5
#pragma unroll 1
    for (int G = 0; G < 72; ++G) {
        const int rb0 = (G & 1) << 1;           // (2G)%4
        const int raSlot = (ra0 + ha >= 5) ? ra0 + ha - 5 : ra0 + ha;
        const int rbSlot = (rb0 + hb) & 3;
        const char* aB = Alds + raSlot * 16384;
        const char* bB = Blds + rbSlot * 16384;
        const int oA1 = offA(G + 1), oA2 = offA(G + 2), oB2 = offB(G + 2);
        const int sA1 = (ra0 + 3 >= 5) ? ra0 - 2 : ra0 + 3;   // (2G+3)%5
        const int sA2 = (ra0 + 4 >= 5) ? ra0 - 1 : ra0 + 4;   // (2G+4)%5

        bf16x8 bq[4][2];
#pragma unroll
        for (int q = 0; q < 4; ++q) {
            bf16x8 aq[2][2];
            if (q == 0) {
#pragma unroll
                for (int ni = 0; ni < 4; ++ni)
#pragma unroll
                    for (int kk = 0; kk < 2; ++kk) {
                        int r = (wn & 64) + ni * 16 + frow;
                        bq[ni][kk] = *(const bf16x8*)(bB + r * 128 +
                                                      (((kk * 4 + fchunk_base) ^ fxor) * 16));
                    }
            }
#pragma unroll
            for (int m2 = 0; m2 < 2; ++m2)
#pragma unroll
                for (int kk = 0; kk < 2; ++kk) {
                    int r = (2 * q + m2) * 16 + frow;
                    aq[m2][kk] = *(const bf16x8*)(aB + r * 128 +
                                                  (((kk * 4 + fchunk_base) ^ fxor) * 16));
                }
            // staging
            if (q == 0) { if (G <= 70) stageA(1, oA1, sA1); }
            if (q == 1) { if (G <= 69) stageA(0, oA2, sA2); }
            if (q == 2) { if (G <= 69) stageB(0, oB2, rb0); }
            if (q == 3) { if (G <= 69) stageB(1, oB2, (rb0 + 1) & 3); }

            __builtin_amdgcn_sched_barrier(0);
            __builtin_amdgcn_s_barrier();
            __builtin_amdgcn_sched_barrier(0);

            __builtin_amdgcn_s_setprio(1);
#pragma unroll
            for (int kk = 0; kk < 2; ++kk)
#pragma unroll
                for (int ni = 0; ni < 4; ++ni)
#pragma unroll
                    for (int m2 = 0; m2 < 2; ++m2)
                        acc[2 * q + m2][ni] = __builtin_amdgcn_mfma_f32_16x16x32_bf16(
                            aq[m2][kk], bq[ni][kk], acc[2 * q + m2][ni], 0, 0, 0);
            __builtin_amdgcn_s_setprio(0);

            if (q == 3) {
                if (G <= 69) {
                    asm volatile("s_waitcnt vmcnt(6)" ::: "memory");
                } else if (G == 70) {
                    asm volatile("s_waitcnt vmcnt(0)" ::: "memory");
                }
            }
            __builtin_amdgcn_sched_barrier(0);
            __builtin_amdgcn_s_barrier();
            __builtin_amdgcn_sched_barrier(0);
        }
        ra0 = (ra0 + 2 >= 5) ? ra0 - 3 : ra0 + 2;
    }

    // epilogue
#pragma unroll
    for (int mi = 0; mi < 8; ++mi) {
#pragma unroll
        for (int ni = 0; ni < 4; ++ni) {
#pragma unroll
            for (int r = 0; r < 4; ++r) {
                int m = mt * 256 + wm + mi * 16 + (l >> 4) * 4 + r;
                int co = nt * 256 + wn + ni * 16 + (l & 15);
                out[(((size_t)(b * 4096 + m)) << 9) + co] = acc[mi][ni][r];
            }
        }
    }
}

// ---------------- launch ----------------

extern "C" void kernel_launch(void* const* d_in, const int* in_sizes, int n_in,
                              void* d_out, int out_size, void* d_ws, size_t ws_size,
                              hipStream_t stream) {
    const float* x = (const float*)d_in[0];
    const float* style = (const float*)d_in[1];
    const float* kern = (const float*)d_in[2];
    float* out = (float*)d_out;

    char* ws = (char*)d_ws;
    ushort* xpad = (ushort*)ws;                                // 35,684,352 B
    ushort* wT = (ushort*)(ws + 35684352);                     // 37,748,736 B
    float* Q = (float*)(ws + 35684352 + 37748736);             // 1,048,576 B
    float* sig = (float*)(ws + 35684352 + 37748736 + 1048576); // 16,384 B

    (void)hipFuncSetAttribute((const void*)conv_mfma,
                              hipFuncAttributeMaxDynamicSharedMemorySize, 147456);

    k_q<<<1024, 256, 0, stream>>>(kern, Q);
    k_sigma<<<8, 512, 0, stream>>>(style, Q, sig);
    k_wt<<<dim3(64, 9, 8), 256, 0, stream>>>(kern, style, sig, wT);
    k_xpad<<<8712, 256, 0, stream>>>(x, xpad);
    conv_mfma<<<256, 512, 147456, stream>>>(xpad, wT, out);
}

// Round 4
// 190.182 us; speedup vs baseline: 1.3276x; 1.0260x over previous
//
#include <hip/hip_runtime.h>

typedef __bf16 bf16x8 __attribute__((ext_vector_type(8)));
typedef float f32x4 __attribute__((ext_vector_type(4)));

#define SCALE_F 0.014731391274719738f   /* 1/sqrt(9*512) */
#define SCALE2_F 2.170138888888889e-4f  /* 1/4608 */

__device__ __forceinline__ ushort f2bf(float f) {
    uint x = __float_as_uint(f);
    uint r = (x + 0x7fffu + ((x >> 16) & 1u)) >> 16;
    return (ushort)r;
}

__device__ __forceinline__ void async_cp16(const void* g, void* l) {
    __builtin_amdgcn_global_load_lds(
        (const __attribute__((address_space(1))) void*)g,
        (__attribute__((address_space(3))) void*)l, 16, 0, 0);
}

// ---------------- prep kernels (unchanged) ----------------

__global__ void k_q(const float* __restrict__ kern, float* __restrict__ Q) {
    int idx = blockIdx.x * 256 + threadIdx.x;
    float s = 0.f;
#pragma unroll
    for (int t = 0; t < 9; ++t) { float v = kern[t * 262144 + idx]; s += v * v; }
    Q[idx] = s * SCALE2_F;
}

__global__ void k_sigma(const float* __restrict__ style, const float* __restrict__ Q,
                        float* __restrict__ sig) {
    __shared__ float s2[512];
    int b = blockIdx.x, t = threadIdx.x;
    float s = style[b * 512 + t];
    s2[t] = s * s;
    __syncthreads();
    float acc = 0.f;
#pragma unroll 8
    for (int ci = 0; ci < 512; ++ci) acc += s2[ci] * Q[ci * 512 + t];
    sig[b * 512 + t] = rsqrtf(acc + 1e-8f);
}

__global__ void k_wt(const float* __restrict__ kern, const float* __restrict__ style,
                     const float* __restrict__ sig, ushort* __restrict__ wT) {
    __shared__ ushort tile[64 * 65];
    int b = blockIdx.z, tap = blockIdx.y;
    int ci0 = (blockIdx.x >> 3) << 6, co0 = (blockIdx.x & 7) << 6;
    int t = threadIdx.x;
    int col = t & 63, rq = t >> 6;
#pragma unroll
    for (int r = 0; r < 16; ++r) {
        int ci_l = r * 4 + rq;
        float v = kern[(size_t)(tap * 512 + ci0 + ci_l) * 512 + co0 + col];
        float val = SCALE_F * v * style[b * 512 + ci0 + ci_l] * sig[b * 512 + co0 + col];
        tile[ci_l * 65 + col] = f2bf(val);
    }
    __syncthreads();
#pragma unroll
    for (int r = 0; r < 4; ++r) {
        int q = r * 256 + t;
        int co_l = q >> 4, ciq = (q & 15) << 2;
        uint lo = (uint)tile[ciq * 65 + co_l] | ((uint)tile[(ciq + 1) * 65 + co_l] << 16);
        uint hi = (uint)tile[(ciq + 2) * 65 + co_l] | ((uint)tile[(ciq + 3) * 65 + co_l] << 16);
        *(uint2*)(&wT[((size_t)(b * 9 + tap) * 512 + co0 + co_l) * 512 + ci0 + ciq]) =
            make_uint2(lo, hi);
    }
}

__global__ void k_xpad(const float* __restrict__ x, ushort* __restrict__ xp) {
    int idx = blockIdx.x * 256 + threadIdx.x;
    int pos = idx >> 6, e = idx & 63;
    int b = pos / 4356, rem = pos - b * 4356;
    int hp = rem / 66, wp = rem - hp * 66;
    int ci0 = e << 3;
    uint4 o = make_uint4(0u, 0u, 0u, 0u);
    if (hp >= 1 && hp <= 64 && wp >= 1 && wp <= 64) {
        const float4* s =
            (const float4*)(x + (((size_t)(b * 4096 + (hp - 1) * 64 + (wp - 1))) << 9) + ci0);
        float4 v0 = s[0], v1 = s[1];
        o.x = (uint)f2bf(v0.x) | ((uint)f2bf(v0.y) << 16);
        o.y = (uint)f2bf(v0.z) | ((uint)f2bf(v0.w) << 16);
        o.z = (uint)f2bf(v1.x) | ((uint)f2bf(v1.y) << 16);
        o.w = (uint)f2bf(v1.z) | ((uint)f2bf(v1.w) << 16);
    }
    *(uint4*)(xp + (((size_t)pos) << 9) + ci0) = o;
}

// ---------------- main conv: 256x256 tile, BK=64, 8 waves ----------------
// R4: ONE barrier per K-tile, plain 2-deep double buffer (A[2],B[2] of 32KB each,
// 128KB LDS). All 8 stages for K-tile G+1 issued at region start (~full region
// before the vmcnt(0) drain -> latency covered). No mid-region barriers: compiler
// interleaves ds_read issue with MFMAs (LDS pipe || MFMA pipe), waves stagger.
__global__ __launch_bounds__(512, 2) void conv_mfma(const ushort* __restrict__ xpad,
                                                    const ushort* __restrict__ wT,
                                                    float* __restrict__ out) {
    extern __shared__ char lds[];

    // XCD swizzle: chunk of 32 contiguous logical ids (= one batch b) per XCD.
    const int wg = blockIdx.x;                      // 0..255
    const int swz = (wg & 7) * 32 + (wg >> 3);      // bijective (256 % 8 == 0)
    const int mt = swz & 15;
    const int nt = (swz >> 4) & 1;
    const int b = swz >> 5;

    const int tid = threadIdx.x;
    const int l = tid & 63, wv = tid >> 6;
    const int wm = (wv >> 2) * 128;
    const int wn = (wv & 3) * 64;
    const int ha = wv >> 2;          // A half this wave reads
    const int hb = (wv & 3) >> 1;    // B half this wave reads

    // staging geometry: lane l covers row (l>>3) of an 8-row group, stored chunk l&7
    const int rl = l >> 3;
    const int g = (l & 7) ^ rl;      // data chunk pre-swizzle
    const ushort* baseA[2][2];
    const ushort* baseB[2][2];
    int ldsoff[2][2];
#pragma unroll
    for (int h = 0; h < 2; ++h)
#pragma unroll
        for (int i = 0; i < 2; ++i) {
            int rloc = wv * 16 + i * 8 + rl;   // 0..127 within half
            int R = h * 128 + rloc;            // 0..255 tile row
            baseA[h][i] = xpad + ((size_t)((b * 66 + mt * 4 + (R >> 6)) * 66 + (R & 63))) * 512 + g * 8;
            baseB[h][i] = wT + ((size_t)(b * 9 * 512 + nt * 256 + R)) * 512 + g * 8;
            ldsoff[h][i] = (h * 128 + wv * 16 + i * 8) * 128;
        }

    auto offA = [](int t) -> int {
        int tap = t >> 3;
        int ky = (tap * 11) >> 5;
        int kx = tap - ky * 3;
        return (ky * 66 + kx) * 512 + ((t & 7) << 6);
    };
    auto offB = [](int t) -> int { return (t >> 3) * 262144 + ((t & 7) << 6); };

    auto stageAll = [&](int t, int buf) {
        int oA = offA(t), oB = offB(t);
        char* Ab = lds + buf * 32768;
        char* Bb = lds + 65536 + buf * 32768;
#pragma unroll
        for (int h = 0; h < 2; ++h)
#pragma unroll
            for (int i = 0; i < 2; ++i)
                async_cp16(baseA[h][i] + oA, Ab + ldsoff[h][i]);
#pragma unroll
        for (int h = 0; h < 2; ++h)
#pragma unroll
            for (int i = 0; i < 2; ++i)
                async_cp16(baseB[h][i] + oB, Bb + ldsoff[h][i]);
    };

    f32x4 acc[8][4];
#pragma unroll
    for (int mi = 0; mi < 8; ++mi)
#pragma unroll
        for (int ni = 0; ni < 4; ++ni) acc[mi][ni] = (f32x4){0.f, 0.f, 0.f, 0.f};

    // prologue: stage K-tile 0 into buf 0, drain, barrier
    stageAll(0, 0);
    asm volatile("s_waitcnt vmcnt(0)" ::: "memory");
    __builtin_amdgcn_sched_barrier(0);
    __builtin_amdgcn_s_barrier();
    __builtin_amdgcn_sched_barrier(0);

    const int frow = l & 15;
    const int fchunk_base = l >> 4;   // 0..3
    const int fxor = l & 7;

#pragma unroll 1
    for (int G = 0; G < 72; ++G) {
        const int cur = G & 1;
        const char* aB = lds + cur * 32768 + ha * 16384;
        const char* bB = lds + 65536 + cur * 32768 + hb * 16384;

        // issue next tile's staging first (earliest VMEM issue, ~full region of cover)
        if (G <= 70) stageAll(G + 1, cur ^ 1);

        // B fragments for the whole K-tile (register-resident across all 4 phases)
        bf16x8 bq[4][2];
#pragma unroll
        for (int kk = 0; kk < 2; ++kk)
#pragma unroll
            for (int ni = 0; ni < 4; ++ni) {
                int r = (wn & 64) + ni * 16 + frow;
                bq[ni][kk] = *(const bf16x8*)(bB + r * 128 +
                                              (((kk * 4 + fchunk_base) ^ fxor) * 16));
            }

#pragma unroll
        for (int q = 0; q < 4; ++q) {
            bf16x8 aq[2][2];
#pragma unroll
            for (int m2 = 0; m2 < 2; ++m2)
#pragma unroll
                for (int kk = 0; kk < 2; ++kk) {
                    int r = (2 * q + m2) * 16 + frow;
                    aq[m2][kk] = *(const bf16x8*)(aB + r * 128 +
                                                  (((kk * 4 + fchunk_base) ^ fxor) * 16));
                }
            __builtin_amdgcn_s_setprio(1);
#pragma unroll
            for (int kk = 0; kk < 2; ++kk)
#pragma unroll
                for (int ni = 0; ni < 4; ++ni)
#pragma unroll
                    for (int m2 = 0; m2 < 2; ++m2)
                        acc[2 * q + m2][ni] = __builtin_amdgcn_mfma_f32_16x16x32_bf16(
                            aq[m2][kk], bq[ni][kk], acc[2 * q + m2][ni], 0, 0, 0);
            __builtin_amdgcn_s_setprio(0);
        }

        // region end: drain this region's stages, barrier (skip after last tile)
        if (G <= 70) {
            asm volatile("s_waitcnt vmcnt(0)" ::: "memory");
            __builtin_amdgcn_sched_barrier(0);
            __builtin_amdgcn_s_barrier();
            __builtin_amdgcn_sched_barrier(0);
        }
    }

    // epilogue: D[(l>>4)*4+r][l&15] per 16x16 fragment
#pragma unroll
    for (int mi = 0; mi < 8; ++mi) {
#pragma unroll
        for (int ni = 0; ni < 4; ++ni) {
#pragma unroll
            for (int r = 0; r < 4; ++r) {
                int m = mt * 256 + wm + mi * 16 + (l >> 4) * 4 + r;
                int co = nt * 256 + wn + ni * 16 + (l & 15);
                out[(((size_t)(b * 4096 + m)) << 9) + co] = acc[mi][ni][r];
            }
        }
    }
}

// ---------------- launch ----------------

extern "C" void kernel_launch(void* const* d_in, const int* in_sizes, int n_in,
                              void* d_out, int out_size, void* d_ws, size_t ws_size,
                              hipStream_t stream) {
    const float* x = (const float*)d_in[0];
    const float* style = (const float*)d_in[1];
    const float* kern = (const float*)d_in[2];
    float* out = (float*)d_out;

    char* ws = (char*)d_ws;
    ushort* xpad = (ushort*)ws;                                // 35,684,352 B
    ushort* wT = (ushort*)(ws + 35684352);                     // 37,748,736 B
    float* Q = (float*)(ws + 35684352 + 37748736);             // 1,048,576 B
    float* sig = (float*)(ws + 35684352 + 37748736 + 1048576); // 16,384 B

    (void)hipFuncSetAttribute((const void*)conv_mfma,
                              hipFuncAttributeMaxDynamicSharedMemorySize, 131072);

    k_q<<<1024, 256, 0, stream>>>(kern, Q);
    k_sigma<<<8, 512, 0, stream>>>(style, Q, sig);
    k_wt<<<dim3(64, 9, 8), 256, 0, stream>>>(kern, style, sig, wT);
    k_xpad<<<8712, 256, 0, stream>>>(x, xpad);
    conv_mfma<<<256, 512, 131072, stream>>>(xpad, wT, out);
}